// Round 1
// baseline (348.323 us; speedup 1.0000x reference)
//
#include <hip/hip_runtime.h>

#define IN_F 4096
#define OUT_F 14336
#define NG 32          // groups per row (4096/128)
#define NB 8           // batch

// ---------------- Kernel 1: RMSNorm -> xn in workspace ----------------
__global__ __launch_bounds__(256) void rmsnorm_k(const float* __restrict__ x,
                                                 const float* __restrict__ nw,
                                                 float* __restrict__ xn) {
  const int b = blockIdx.x;
  const int t = threadIdx.x;
  const float* xr = x + b * IN_F;
  float4 v[4];
  float ss = 0.f;
#pragma unroll
  for (int i = 0; i < 4; ++i) {
    v[i] = reinterpret_cast<const float4*>(xr)[i * 256 + t];
    ss += v[i].x * v[i].x + v[i].y * v[i].y + v[i].z * v[i].z + v[i].w * v[i].w;
  }
#pragma unroll
  for (int m = 1; m < 64; m <<= 1) ss += __shfl_xor(ss, m, 64);
  __shared__ float red[4];
  if ((t & 63) == 0) red[t >> 6] = ss;
  __syncthreads();
  ss = red[0] + red[1] + red[2] + red[3];
  const float r = rsqrtf(ss * (1.0f / IN_F) + 1e-6f);
#pragma unroll
  for (int i = 0; i < 4; ++i) {
    float4 w = reinterpret_cast<const float4*>(nw)[i * 256 + t];
    float4 o;
    o.x = v[i].x * r * w.x;
    o.y = v[i].y * r * w.y;
    o.z = v[i].z * r * w.z;
    o.w = v[i].w * r * w.w;
    reinterpret_cast<float4*>(xn + b * IN_F)[i * 256 + t] = o;
  }
}

// ---------------- Kernel 2: dequant GEMV ----------------
// One wave handles 4 output rows. Lane l, iteration k: columns k*256 + 4l..+3
// (all 4 columns in the same quant group since 4 | 128).
__global__ __launch_bounds__(256) void gemv_k(const int* __restrict__ W,
                                              const float2* __restrict__ smv,
                                              const float* __restrict__ xn,
                                              const float* __restrict__ bias,
                                              float* __restrict__ out) {
  const int t = threadIdx.x;
  const int lane = t & 63;
  const int wave = t >> 6;
  const int row0 = (blockIdx.x * 4 + wave) * 4;  // 4 rows per wave

  float acc[4][NB];
#pragma unroll
  for (int rr = 0; rr < 4; ++rr)
#pragma unroll
    for (int b = 0; b < NB; ++b) acc[rr][b] = 0.f;

  const int lcol = lane * 4;
  for (int k = 0; k < 16; ++k) {
    const int col = k * 256 + lcol;
    float4 xv[NB];
#pragma unroll
    for (int b = 0; b < NB; ++b)
      xv[b] = *reinterpret_cast<const float4*>(xn + b * IN_F + col);
    const int g = col >> 7;  // group index: 2k + lane/32
#pragma unroll
    for (int rr = 0; rr < 4; ++rr) {
      const int o = row0 + rr;
      const int4 q = *reinterpret_cast<const int4*>(W + o * IN_F + col);
      const float2 sm = smv[o * NG + g];
      const float w0 = (float)q.x * sm.x + sm.y;
      const float w1 = (float)q.y * sm.x + sm.y;
      const float w2 = (float)q.z * sm.x + sm.y;
      const float w3 = (float)q.w * sm.x + sm.y;
#pragma unroll
      for (int b = 0; b < NB; ++b) {
        acc[rr][b] = fmaf(w0, xv[b].x, acc[rr][b]);
        acc[rr][b] = fmaf(w1, xv[b].y, acc[rr][b]);
        acc[rr][b] = fmaf(w2, xv[b].z, acc[rr][b]);
        acc[rr][b] = fmaf(w3, xv[b].w, acc[rr][b]);
      }
    }
  }

  // Reduce each of the 32 partials across the 64 lanes (butterfly).
#pragma unroll
  for (int rr = 0; rr < 4; ++rr)
#pragma unroll
    for (int b = 0; b < NB; ++b) {
      float v = acc[rr][b];
#pragma unroll
      for (int m = 1; m < 64; m <<= 1) v += __shfl_xor(v, m, 64);
      acc[rr][b] = v;
    }

  if (lane < 32) {
    const int rr = lane >> 3;
    const int b = lane & 7;
    const int o = row0 + rr;
    out[b * OUT_F + o] = acc[rr][b] + bias[o];
  }
}

extern "C" void kernel_launch(void* const* d_in, const int* in_sizes, int n_in,
                              void* d_out, int out_size, void* d_ws, size_t ws_size,
                              hipStream_t stream) {
  const float* x = (const float*)d_in[0];
  const int* W = (const int*)d_in[1];
  const float2* smv = (const float2*)d_in[2];
  const float* nw = (const float*)d_in[3];
  const float* bias = (const float*)d_in[4];
  float* out = (float*)d_out;
  float* xn = (float*)d_ws;  // 8 * 4096 floats = 128 KB

  rmsnorm_k<<<NB, 256, 0, stream>>>(x, nw, xn);
  gemv_k<<<OUT_F / 16, 256, 0, stream>>>(W, smv, xn, bias, out);
}

// Round 2
// 314.828 us; speedup vs baseline: 1.1064x; 1.1064x over previous
//
#include <hip/hip_runtime.h>

#define IN_F 4096
#define OUT_F 14336
#define NG 32          // groups per row (4096/128)
#define NB 8           // batch
#define RPW 7          // rows per wave
#define RPB 28         // rows per block (4 waves * 7)
#define NBLK 512       // 14336 / 28 ; exactly 2 blocks per CU

typedef int v4i __attribute__((ext_vector_type(4)));

// ---------------- Kernel 1: RMSNorm -> xn in workspace ----------------
__global__ __launch_bounds__(1024) void rmsnorm_k(const float* __restrict__ x,
                                                  const float* __restrict__ nw,
                                                  float* __restrict__ xn) {
  const int b = blockIdx.x;
  const int t = threadIdx.x;  // 1024 threads, one float4 each (4096 floats)
  float4 v = reinterpret_cast<const float4*>(x + b * IN_F)[t];
  float ss = v.x * v.x + v.y * v.y + v.z * v.z + v.w * v.w;
#pragma unroll
  for (int m = 1; m < 64; m <<= 1) ss += __shfl_xor(ss, m, 64);
  __shared__ float red[16];
  if ((t & 63) == 0) red[t >> 6] = ss;
  __syncthreads();
  float tot = 0.f;
#pragma unroll
  for (int i = 0; i < 16; ++i) tot += red[i];
  const float r = rsqrtf(tot * (1.0f / IN_F) + 1e-6f);
  float4 w = reinterpret_cast<const float4*>(nw)[t];
  float4 o;
  o.x = v.x * r * w.x;
  o.y = v.y * r * w.y;
  o.z = v.z * r * w.z;
  o.w = v.w * r * w.w;
  reinterpret_cast<float4*>(xn + b * IN_F)[t] = o;
}

// ---------------- Kernel 2: dequant GEMV ----------------
// 512 blocks (exactly 2/CU), 4 waves/block, 7 rows/wave.
// Lane l, iteration k: columns k*256 + 4l..+3 (4 cols share a quant group).
// W is streamed nontemporally (no reuse -> keep xn/smv resident in L2).
__global__ __launch_bounds__(256, 2) void gemv_k(const int* __restrict__ W,
                                                 const float2* __restrict__ smv,
                                                 const float* __restrict__ xn,
                                                 const float* __restrict__ bias,
                                                 float* __restrict__ out) {
  const int t = threadIdx.x;
  const int lane = t & 63;
  const int wave = t >> 6;
  const int row0 = blockIdx.x * RPB + wave * RPW;

  float acc[RPW][NB];
#pragma unroll
  for (int rr = 0; rr < RPW; ++rr)
#pragma unroll
    for (int b = 0; b < NB; ++b) acc[rr][b] = 0.f;

  const int lcol = lane * 4;
  for (int k = 0; k < 16; ++k) {
    const int col = k * 256 + lcol;
    float4 xv[NB];
#pragma unroll
    for (int b = 0; b < NB; ++b)
      xv[b] = *reinterpret_cast<const float4*>(xn + b * IN_F + col);
    const int g = col >> 7;  // 2k + lane/32
#pragma unroll
    for (int rr = 0; rr < RPW; ++rr) {
      const int o = row0 + rr;
      const v4i q = __builtin_nontemporal_load(
          reinterpret_cast<const v4i*>(W + o * IN_F + col));
      const float2 sm = smv[o * NG + g];
      const float w0 = fmaf((float)q.x, sm.x, sm.y);
      const float w1 = fmaf((float)q.y, sm.x, sm.y);
      const float w2 = fmaf((float)q.z, sm.x, sm.y);
      const float w3 = fmaf((float)q.w, sm.x, sm.y);
#pragma unroll
      for (int b = 0; b < NB; ++b) {
        acc[rr][b] = fmaf(w0, xv[b].x, acc[rr][b]);
        acc[rr][b] = fmaf(w1, xv[b].y, acc[rr][b]);
        acc[rr][b] = fmaf(w2, xv[b].z, acc[rr][b]);
        acc[rr][b] = fmaf(w3, xv[b].w, acc[rr][b]);
      }
    }
  }

  // Epilogue: LDS transpose (odd stride 225 -> conflict-free both directions),
  // then 224 threads each tree-sum 64 lane-partials for one output.
  __shared__ float p[64][225];
#pragma unroll
  for (int rr = 0; rr < RPW; ++rr)
#pragma unroll
    for (int b = 0; b < NB; ++b)
      p[lane][wave * (RPW * NB) + rr * NB + b] = acc[rr][b];
  __syncthreads();

  if (t < RPB * NB) {  // 224 outputs per block
    float s0 = 0.f, s1 = 0.f, s2 = 0.f, s3 = 0.f;
#pragma unroll
    for (int l = 0; l < 64; l += 4) {
      s0 += p[l + 0][t];
      s1 += p[l + 1][t];
      s2 += p[l + 2][t];
      s3 += p[l + 3][t];
    }
    const int r = t >> 3;   // local row
    const int b = t & 7;    // batch
    const int o = blockIdx.x * RPB + r;
    out[b * OUT_F + o] = (s0 + s1) + (s2 + s3) + bias[o];
  }
}

extern "C" void kernel_launch(void* const* d_in, const int* in_sizes, int n_in,
                              void* d_out, int out_size, void* d_ws, size_t ws_size,
                              hipStream_t stream) {
  const float* x = (const float*)d_in[0];
  const int* W = (const int*)d_in[1];
  const float2* smv = (const float2*)d_in[2];
  const float* nw = (const float*)d_in[3];
  const float* bias = (const float*)d_in[4];
  float* out = (float*)d_out;
  float* xn = (float*)d_ws;  // 8 * 4096 floats = 128 KB

  rmsnorm_k<<<NB, 1024, 0, stream>>>(x, nw, xn);
  gemv_k<<<NBLK, 256, 0, stream>>>(W, smv, xn, bias, out);
}